// Round 26
// baseline (104.738 us; speedup 1.0000x reference)
//
#include <hip/hip_runtime.h>
#include <math.h>

#define BATCH 4
#define CH    96
#define HH    48
#define WW    48
#define HWPIX (HH*WW)         // 2304
#define NPIX  (BATCH*HWPIX)   // 9216
#define WIN   13
#define WIN2  169
#define HALF  6
#define TOPK  8
#define NEGV  (-1000000000.0f)

// ---------------------------------------------------------------------------
// K0: pack weights into quad layouts (r25, passing):
//     w1Q[c4*192 + j] = float4(w1[j][4c4..4c4+3])
//     w2Q[j4*96  + c] = float4(w2[c][4j4..4j4+3])
// ---------------------------------------------------------------------------
__global__ __launch_bounds__(256) void k0_wq(
    const float* __restrict__ w1, const float* __restrict__ w2,
    float4* __restrict__ w1Q, float4* __restrict__ w2Q)
{
    int i = blockIdx.x * 256 + threadIdx.x;   // 36 * 256 = 9216
    if (i < 4608) {
        int c4 = i / 192, j = i % 192;
        w1Q[c4 * 192 + j] = *(const float4*)(w1 + j * 96 + c4 * 4);
    } else {
        int k = i - 4608;
        int j4 = k / 96, c = k % 96;
        w2Q[j4 * 96 + c] = *(const float4*)(w2 + c * 192 + j4 * 4);
    }
}

// ---------------------------------------------------------------------------
// K1: x -> xt2 chunk-major + invn/mu/rstd (r19, passing).
// ---------------------------------------------------------------------------
__global__ __launch_bounds__(256) void k1_prep(
    const float* __restrict__ x, float* __restrict__ xt2,
    float* __restrict__ invn, float* __restrict__ muv, float* __restrict__ rsd)
{
    __shared__ float lds[96][17];
    int bid = blockIdx.x;          // 576 = 4 batches * 144 tiles
    int b   = bid / 144;
    int p0  = (bid % 144) * 16;
    int t   = threadIdx.x;

    #pragma unroll
    for (int it = 0; it < 6; ++it) {
        int e = t + it * 256;
        int c = e >> 4;
        int p = e & 15;
        lds[c][p] = x[(b * CH + c) * HWPIX + p0 + p];
    }
    __syncthreads();

    if (t < 16) {
        float s = 0.f, ss = 0.f;
        #pragma unroll
        for (int c = 0; c < CH; ++c) { float v = lds[c][t]; s += v; ss += v * v; }
        int gpix = b * HWPIX + p0 + t;
        invn[gpix] = 1.0f / fmaxf(sqrtf(ss), 1e-12f);
        float m = s * (1.0f / 96.0f);
        muv[gpix] = m;
        rsd[gpix] = rsqrtf(ss * (1.0f / 96.0f) - m * m + 1e-5f);
    }

    float4* x4 = (float4*)xt2;
    for (int i = t; i < 384; i += 256) {
        int p = i & 15;
        int s = i >> 4;
        float4 v = make_float4(lds[4*s][p], lds[4*s+1][p],
                               lds[4*s+2][p], lds[4*s+3][p]);
        x4[s * NPIX + b * HWPIX + p0 + p] = v;
    }
}

// ---------------------------------------------------------------------------
// K2: one pixel per wave, 2304 blocks x 256 thr, chunk-major reads,
//     ballot top-8, LN stats from k1 (r16/r19 math, best measured ~31us).
//     CHUNK_ENH selects the enh store layout:
//       false: row-major (fallback k3)   true: chunk-major (split k3a/k3b)
// ---------------------------------------------------------------------------
template <bool CHUNK_ENH>
__global__ __launch_bounds__(256) void k2_knn(
    const float* __restrict__ xt2, const float* __restrict__ invn,
    const float* __restrict__ muv, const float* __restrict__ rsd,
    const float* __restrict__ lnw, const float* __restrict__ lnb,
    float* __restrict__ enh)
{
    __shared__ float own[4][96];
    int t    = threadIdx.x;
    int wv   = t >> 6;
    int lane = t & 63;
    int gp   = blockIdx.x * 4 + wv;
    int b    = gp / HWPIX;
    int p    = gp - b * HWPIX;
    int py   = p / WW;
    int px   = p - py * WW;
    const float4* x4 = (const float4*)xt2;

    float4 ownv = make_float4(0.f, 0.f, 0.f, 0.f);
    if (lane < 24) {
        ownv = x4[lane * NPIX + gp];
        ((float4*)(own[wv]))[lane] = ownv;
    }
    float inp = invn[gp];
    float mu  = muv[gp];
    float rs  = rsd[gp];

    float v0 = -2e9f, v1 = -2e9f, v2 = -2e9f;
    const float4* ov = (const float4*)(own[wv]);
    #pragma unroll
    for (int k = 0; k < 3; ++k) {
        int n = lane + 64 * k;
        float sim = -2e9f;
        if (n < WIN2) {
            int dy = n / WIN - HALF;
            int dx = n - (dy + HALF) * WIN - HALF;
            int ny = py + dy, nx = px + dx;
            if (ny >= 0 && ny < HH && nx >= 0 && nx < WW) {
                int q = b * HWPIX + ny * WW + nx;
                float inq = invn[q];
                const float4* rp = x4 + q;
                float ax = 0.f, ay = 0.f, az = 0.f, aw = 0.f;
                #pragma unroll
                for (int s = 0; s < 24; ++s) {
                    float4 a  = ov[s];
                    float4 bb = rp[s * NPIX];
                    ax += a.x * bb.x; ay += a.y * bb.y;
                    az += a.z * bb.z; aw += a.w * bb.w;
                }
                sim = ((ax + ay) + (az + aw)) * inp * inq;
            } else {
                sim = NEGV;
            }
        }
        if (k == 0) v0 = sim; else if (k == 1) v1 = sim; else v2 = sim;
    }

    float tv[TOPK]; int tn[TOPK];
    #pragma unroll
    for (int r = 0; r < TOPK; ++r) {
        float m = fmaxf(fmaxf(v0, v1), v2);
        #pragma unroll
        for (int off = 1; off < 64; off <<= 1)
            m = fmaxf(m, __shfl_xor(m, off));
        unsigned long long m0 = __ballot(v0 == m);
        unsigned long long m1 = __ballot(v1 == m);
        unsigned long long m2 = __ballot(v2 == m);
        int n;
        if (m0)      n = (int)__builtin_ctzll(m0);
        else if (m1) n = 64 + (int)__builtin_ctzll(m1);
        else         n = 128 + (int)__builtin_ctzll(m2);
        tv[r] = m; tn[r] = n;
        int kk = n >> 6, ll = n & 63;
        if (ll == lane) {
            if (kk == 0)      v0 = -2e9f;
            else if (kk == 1) v1 = -2e9f;
            else              v2 = -2e9f;
        }
    }

    float wts[TOPK]; int qn[TOPK];
    float wsum = 0.f;
    #pragma unroll
    for (int r = 0; r < TOPK; ++r) {
        float e = expf(tv[r] - tv[0]);
        wts[r] = e; wsum += e;
        int n  = tn[r];
        int dy = n / WIN - HALF;
        int dx = n - (dy + HALF) * WIN - HALF;
        int gy = min(max(py + dy, 0), HH - 1);
        int gx = min(max(px + dx, 0), WW - 1);
        qn[r]  = b * HWPIX + gy * WW + gx;
    }
    float winv = 1.0f / wsum;

    if (lane < 24) {
        const float4* base = x4 + lane * NPIX;
        float4 g = make_float4(0.f, 0.f, 0.f, 0.f);
        #pragma unroll
        for (int r = 0; r < TOPK; ++r) {
            float4 f = base[qn[r]];
            float w = wts[r];
            g.x += w * f.x; g.y += w * f.y;
            g.z += w * f.z; g.w += w * f.w;
        }
        float4 lw = ((const float4*)lnw)[lane];
        float4 lb = ((const float4*)lnb)[lane];
        float4 e;
        e.x = g.x * winv + (ownv.x - mu) * rs * lw.x + lb.x;
        e.y = g.y * winv + (ownv.y - mu) * rs * lw.y + lb.y;
        e.z = g.z * winv + (ownv.z - mu) * rs * lw.z + lb.z;
        e.w = g.w * winv + (ownv.w - mu) * rs * lw.w + lb.w;
        if (CHUNK_ENH)
            ((float4*)enh)[lane * NPIX + gp] = e;          // chunk-major
        else
            ((float4*)(enh + gp * CH))[lane] = e;          // row-major
    }
}

// ---------------------------------------------------------------------------
// K3a (split path): h = relu(enh2 @ w1 + b1), fully coalesced.
//     1728 blocks (12 jq x 144 px-groups) x 256 thr.
//     lane = pixel (coalesced activation loads), weights wave-uniform s_load.
//     h stored chunk-major: hbuf2[(j/4)*NPIX + p].
// ---------------------------------------------------------------------------
__global__ __launch_bounds__(256) void k3a_h(
    const float* __restrict__ enh2, const float4* __restrict__ w1Q,
    const float* __restrict__ b1, float4* __restrict__ hbuf2)
{
    int bid = blockIdx.x;           // 1728
    int jq  = bid / 144;            // 0..11
    int pg  = bid % 144;
    int t   = threadIdx.x;
    int pix = t & 63;
    int wv  = t >> 6;               // 0..3
    int j0  = jq * 16 + wv * 4;
    int gp  = pg * 64 + pix;
    const float4* e4p = (const float4*)enh2;

    float a0 = 0.f, a1 = 0.f, a2 = 0.f, a3 = 0.f;
    #pragma unroll
    for (int c4 = 0; c4 < 24; ++c4) {
        float4 e  = e4p[c4 * NPIX + gp];        // coalesced
        float4 wA = w1Q[c4 * 192 + j0    ];     // uniform 64B s_load
        float4 wB = w1Q[c4 * 192 + j0 + 1];
        float4 wC = w1Q[c4 * 192 + j0 + 2];
        float4 wD = w1Q[c4 * 192 + j0 + 3];
        a0 += e.x*wA.x + e.y*wA.y + e.z*wA.z + e.w*wA.w;
        a1 += e.x*wB.x + e.y*wB.y + e.z*wB.z + e.w*wB.w;
        a2 += e.x*wC.x + e.y*wC.y + e.z*wC.z + e.w*wC.w;
        a3 += e.x*wD.x + e.y*wD.y + e.z*wD.z + e.w*wD.w;
    }
    float4 h;
    h.x = fmaxf(a0 + b1[j0    ], 0.f);
    h.y = fmaxf(a1 + b1[j0 + 1], 0.f);
    h.z = fmaxf(a2 + b1[j0 + 2], 0.f);
    h.w = fmaxf(a3 + b1[j0 + 3], 0.f);
    hbuf2[(j0 >> 2) * NPIX + gp] = h;           // coalesced
}

// ---------------------------------------------------------------------------
// K3b (split path): out = enh2 + h @ w2 + b2, fully coalesced.
//     864 blocks (6 cq x 144 px-groups) x 256 thr.
// ---------------------------------------------------------------------------
__global__ __launch_bounds__(256) void k3b_out(
    const float* __restrict__ enh2, const float4* __restrict__ hbuf2,
    const float4* __restrict__ w2Q, const float* __restrict__ b2,
    float* __restrict__ out)
{
    int bid = blockIdx.x;           // 864
    int cq  = bid / 144;            // 0..5
    int pg  = bid % 144;
    int t   = threadIdx.x;
    int pix = t & 63;
    int wv  = t >> 6;               // 0..3
    int c0  = cq * 16 + wv * 4;
    int gp  = pg * 64 + pix;

    float s0 = 0.f, s1 = 0.f, s2 = 0.f, s3 = 0.f;
    #pragma unroll 8
    for (int j4 = 0; j4 < 48; ++j4) {
        float4 h  = hbuf2[j4 * NPIX + gp];      // coalesced
        float4 wA = w2Q[j4 * 96 + c0    ];      // uniform 64B s_load
        float4 wB = w2Q[j4 * 96 + c0 + 1];
        float4 wC = w2Q[j4 * 96 + c0 + 2];
        float4 wD = w2Q[j4 * 96 + c0 + 3];
        s0 += h.x*wA.x + h.y*wA.y + h.z*wA.z + h.w*wA.w;
        s1 += h.x*wB.x + h.y*wB.y + h.z*wB.z + h.w*wB.w;
        s2 += h.x*wC.x + h.y*wC.y + h.z*wC.z + h.w*wC.w;
        s3 += h.x*wD.x + h.y*wD.y + h.z*wD.z + h.w*wD.w;
    }
    float4 er = ((const float4*)enh2)[(c0 >> 2) * NPIX + gp];
    int b = gp / HWPIX;
    int p = gp - b * HWPIX;
    out[(b * CH + c0    ) * HWPIX + p] = er.x + s0 + b2[c0    ];
    out[(b * CH + c0 + 1) * HWPIX + p] = er.y + s1 + b2[c0 + 1];
    out[(b * CH + c0 + 2) * HWPIX + p] = er.z + s2 + b2[c0 + 2];
    out[(b * CH + c0 + 3) * HWPIX + p] = er.w + s3 + b2[c0 + 3];
}

// ---------------------------------------------------------------------------
// K3 (fallback path, r25 exact): fused FFN, 8 px/block, 1152 x 192 thr,
//     quad-packed weights, row-major enh.
// ---------------------------------------------------------------------------
__global__ __launch_bounds__(192) void k3_ffn(
    const float* __restrict__ enh, const float4* __restrict__ w1Q,
    const float* __restrict__ b1, const float4* __restrict__ w2Q,
    const float* __restrict__ b2, float* __restrict__ out)
{
    __shared__ float hl[8][200];
    int g  = blockIdx.x;           // 1152 = 4 batches * 288 tiles
    int b  = g / 288;
    int p0 = (g % 288) * 8;
    int t  = threadIdx.x;
    const float4* ebase = (const float4*)(enh + (b * HWPIX + p0) * CH);

    {
        int j = t;
        float a0=0.f,a1=0.f,a2=0.f,a3=0.f,a4=0.f,a5=0.f,a6=0.f,a7=0.f;
        #pragma unroll 4
        for (int c4 = 0; c4 < 24; ++c4) {
            float4 w = w1Q[c4 * 192 + j];
            float4 v0 = ebase[0*24 + c4];
            float4 v1 = ebase[1*24 + c4];
            float4 v2 = ebase[2*24 + c4];
            float4 v3 = ebase[3*24 + c4];
            float4 v4 = ebase[4*24 + c4];
            float4 v5 = ebase[5*24 + c4];
            float4 v6 = ebase[6*24 + c4];
            float4 v7 = ebase[7*24 + c4];
            a0 += v0.x*w.x + v0.y*w.y + v0.z*w.z + v0.w*w.w;
            a1 += v1.x*w.x + v1.y*w.y + v1.z*w.z + v1.w*w.w;
            a2 += v2.x*w.x + v2.y*w.y + v2.z*w.z + v2.w*w.w;
            a3 += v3.x*w.x + v3.y*w.y + v3.z*w.z + v3.w*w.w;
            a4 += v4.x*w.x + v4.y*w.y + v4.z*w.z + v4.w*w.w;
            a5 += v5.x*w.x + v5.y*w.y + v5.z*w.z + v5.w*w.w;
            a6 += v6.x*w.x + v6.y*w.y + v6.z*w.z + v6.w*w.w;
            a7 += v7.x*w.x + v7.y*w.y + v7.z*w.z + v7.w*w.w;
        }
        float bj = b1[j];
        hl[0][j] = fmaxf(a0 + bj, 0.f);
        hl[1][j] = fmaxf(a1 + bj, 0.f);
        hl[2][j] = fmaxf(a2 + bj, 0.f);
        hl[3][j] = fmaxf(a3 + bj, 0.f);
        hl[4][j] = fmaxf(a4 + bj, 0.f);
        hl[5][j] = fmaxf(a5 + bj, 0.f);
        hl[6][j] = fmaxf(a6 + bj, 0.f);
        hl[7][j] = fmaxf(a7 + bj, 0.f);
    }
    __syncthreads();

    {
        int c    = (t >= 96) ? t - 96 : t;
        int half = (t >= 96) ? 1 : 0;
        int q0p  = half * 4;
        const float4* h0 = (const float4*)(&hl[q0p    ][0]);
        const float4* h1 = (const float4*)(&hl[q0p + 1][0]);
        const float4* h2 = (const float4*)(&hl[q0p + 2][0]);
        const float4* h3 = (const float4*)(&hl[q0p + 3][0]);
        float s0 = 0.f, s1 = 0.f, s2 = 0.f, s3 = 0.f;
        #pragma unroll 6
        for (int j4 = 0; j4 < 48; ++j4) {
            float4 w = w2Q[j4 * 96 + c];
            float4 u0 = h0[j4], u1 = h1[j4], u2 = h2[j4], u3 = h3[j4];
            s0 += u0.x*w.x + u0.y*w.y + u0.z*w.z + u0.w*w.w;
            s1 += u1.x*w.x + u1.y*w.y + u1.z*w.z + u1.w*w.w;
            s2 += u2.x*w.x + u2.y*w.y + u2.z*w.z + u2.w*w.w;
            s3 += u3.x*w.x + u3.y*w.y + u3.z*w.z + u3.w*w.w;
        }
        float bc = b2[c];
        int pb = p0 + q0p;
        out[(b * CH + c) * HWPIX + pb + 0] =
            enh[(b * HWPIX + pb + 0) * CH + c] + s0 + bc;
        out[(b * CH + c) * HWPIX + pb + 1] =
            enh[(b * HWPIX + pb + 1) * CH + c] + s1 + bc;
        out[(b * CH + c) * HWPIX + pb + 2] =
            enh[(b * HWPIX + pb + 2) * CH + c] + s2 + bc;
        out[(b * CH + c) * HWPIX + pb + 3] =
            enh[(b * HWPIX + pb + 3) * CH + c] + s3 + bc;
    }
}

// ---------------------------------------------------------------------------
extern "C" void kernel_launch(void* const* d_in, const int* in_sizes, int n_in,
                              void* d_out, int out_size, void* d_ws, size_t ws_size,
                              hipStream_t stream)
{
    const float* x   = (const float*)d_in[0];
    const float* w1  = (const float*)d_in[1];
    const float* b1  = (const float*)d_in[2];
    const float* w2  = (const float*)d_in[3];
    const float* b2  = (const float*)d_in[4];
    const float* lnw = (const float*)d_in[5];
    const float* lnb = (const float*)d_in[6];
    float* out = (float*)d_out;

    // xt2 lives in d_out (k1 writes, k2 reads; final out overwrites it last).
    float* xt2 = out;

    // ws base layout (both paths): enh + invn + muv + rsd + w1Q + w2Q
    float* ws   = (float*)d_ws;
    float* enh  = ws;                        // NPIX*96 = 884736
    float* invn = enh + NPIX * CH;           // NPIX
    float* muv  = invn + NPIX;               // NPIX
    float* rsd  = muv + NPIX;                // NPIX
    float* w1Qf = rsd + NPIX;                // 18432
    float* w2Qf = w1Qf + 192 * 96;           // 18432
    float* hbuf = w2Qf + 192 * 96;           // +1,769,472 (split path only)

    // split path needs 2,718,720 floats = 10,874,880 bytes
    bool split = ws_size >= (size_t)2718720 * sizeof(float);

    hipLaunchKernelGGL(k0_wq, dim3(36), dim3(256), 0, stream,
                       w1, w2, (float4*)w1Qf, (float4*)w2Qf);
    hipLaunchKernelGGL(k1_prep, dim3(576), dim3(256), 0, stream,
                       x, xt2, invn, muv, rsd);
    if (split) {
        hipLaunchKernelGGL(k2_knn<true>, dim3(NPIX / 4), dim3(256), 0, stream,
                           xt2, invn, muv, rsd, lnw, lnb, enh);
        hipLaunchKernelGGL(k3a_h, dim3(1728), dim3(256), 0, stream,
                           enh, (const float4*)w1Qf, b1, (float4*)hbuf);
        hipLaunchKernelGGL(k3b_out, dim3(864), dim3(256), 0, stream,
                           enh, (const float4*)hbuf, (const float4*)w2Qf, b2, out);
    } else {
        hipLaunchKernelGGL(k2_knn<false>, dim3(NPIX / 4), dim3(256), 0, stream,
                           xt2, invn, muv, rsd, lnw, lnb, enh);
        hipLaunchKernelGGL(k3_ffn, dim3(1152), dim3(192), 0, stream,
                           enh, (const float4*)w1Qf, b1, (const float4*)w2Qf, b2, out);
    }
}

// Round 27
// 74.412 us; speedup vs baseline: 1.4075x; 1.4075x over previous
//
#include <hip/hip_runtime.h>
#include <math.h>

#define BATCH 4
#define CH    96
#define HH    48
#define WW    48
#define HWPIX (HH*WW)         // 2304
#define NPIX  (BATCH*HWPIX)   // 9216
#define WIN   13
#define WIN2  169
#define HALF  6
#define TOPK  8
#define NEGV  (-1000000000.0f)

// ---------------------------------------------------------------------------
// K0: pack weights into quad layouts (r25, passing):
//     w1Q[c4*192 + j] = float4(w1[j][4c4..4c4+3])
//     w2Q[j4*96  + c] = float4(w2[c][4j4..4j4+3])
// ---------------------------------------------------------------------------
__global__ __launch_bounds__(256) void k0_wq(
    const float* __restrict__ w1, const float* __restrict__ w2,
    float4* __restrict__ w1Q, float4* __restrict__ w2Q)
{
    int i = blockIdx.x * 256 + threadIdx.x;   // 36 * 256 = 9216
    if (i < 4608) {
        int c4 = i / 192, j = i % 192;
        w1Q[c4 * 192 + j] = *(const float4*)(w1 + j * 96 + c4 * 4);
    } else {
        int k = i - 4608;
        int j4 = k / 96, c = k % 96;
        w2Q[j4 * 96 + c] = *(const float4*)(w2 + c * 192 + j4 * 4);
    }
}

// ---------------------------------------------------------------------------
// K1: x -> xt2 chunk-major + invn/mu/rstd (r19, passing).
// ---------------------------------------------------------------------------
__global__ __launch_bounds__(256) void k1_prep(
    const float* __restrict__ x, float* __restrict__ xt2,
    float* __restrict__ invn, float* __restrict__ muv, float* __restrict__ rsd)
{
    __shared__ float lds[96][17];
    int bid = blockIdx.x;          // 576 = 4 batches * 144 tiles
    int b   = bid / 144;
    int p0  = (bid % 144) * 16;
    int t   = threadIdx.x;

    #pragma unroll
    for (int it = 0; it < 6; ++it) {
        int e = t + it * 256;      // 1536 = 96c * 16px
        int c = e >> 4;
        int p = e & 15;
        lds[c][p] = x[(b * CH + c) * HWPIX + p0 + p];
    }
    __syncthreads();

    if (t < 16) {
        float s = 0.f, ss = 0.f;
        #pragma unroll
        for (int c = 0; c < CH; ++c) { float v = lds[c][t]; s += v; ss += v * v; }
        int gpix = b * HWPIX + p0 + t;
        invn[gpix] = 1.0f / fmaxf(sqrtf(ss), 1e-12f);
        float m = s * (1.0f / 96.0f);
        muv[gpix] = m;
        rsd[gpix] = rsqrtf(ss * (1.0f / 96.0f) - m * m + 1e-5f);
    }

    float4* x4 = (float4*)xt2;
    for (int i = t; i < 384; i += 256) {
        int p = i & 15;
        int s = i >> 4;
        float4 v = make_float4(lds[4*s][p], lds[4*s+1][p],
                               lds[4*s+2][p], lds[4*s+3][p]);
        x4[s * NPIX + b * HWPIX + p0 + p] = v;
    }
}

// ---------------------------------------------------------------------------
// K2: one pixel per wave, 2304 blocks x 256 thr, chunk-major reads,
//     ballot top-8, LN stats from k1. (r16/r19 exact — best measured ~31us)
// ---------------------------------------------------------------------------
__global__ __launch_bounds__(256) void k2_knn(
    const float* __restrict__ xt2, const float* __restrict__ invn,
    const float* __restrict__ muv, const float* __restrict__ rsd,
    const float* __restrict__ lnw, const float* __restrict__ lnb,
    float* __restrict__ enh)
{
    __shared__ float own[4][96];
    int t    = threadIdx.x;
    int wv   = t >> 6;
    int lane = t & 63;
    int gp   = blockIdx.x * 4 + wv;
    int b    = gp / HWPIX;
    int p    = gp - b * HWPIX;
    int py   = p / WW;
    int px   = p - py * WW;
    const float4* x4 = (const float4*)xt2;

    float4 ownv = make_float4(0.f, 0.f, 0.f, 0.f);
    if (lane < 24) {
        ownv = x4[lane * NPIX + gp];
        ((float4*)(own[wv]))[lane] = ownv;
    }
    float inp = invn[gp];
    float mu  = muv[gp];
    float rs  = rsd[gp];

    float v0 = -2e9f, v1 = -2e9f, v2 = -2e9f;
    const float4* ov = (const float4*)(own[wv]);
    #pragma unroll
    for (int k = 0; k < 3; ++k) {
        int n = lane + 64 * k;
        float sim = -2e9f;
        if (n < WIN2) {
            int dy = n / WIN - HALF;
            int dx = n - (dy + HALF) * WIN - HALF;
            int ny = py + dy, nx = px + dx;
            if (ny >= 0 && ny < HH && nx >= 0 && nx < WW) {
                int q = b * HWPIX + ny * WW + nx;
                float inq = invn[q];
                const float4* rp = x4 + q;
                float ax = 0.f, ay = 0.f, az = 0.f, aw = 0.f;
                #pragma unroll
                for (int s = 0; s < 24; ++s) {
                    float4 a  = ov[s];
                    float4 bb = rp[s * NPIX];
                    ax += a.x * bb.x; ay += a.y * bb.y;
                    az += a.z * bb.z; aw += a.w * bb.w;
                }
                sim = ((ax + ay) + (az + aw)) * inp * inq;
            } else {
                sim = NEGV;
            }
        }
        if (k == 0) v0 = sim; else if (k == 1) v1 = sim; else v2 = sim;
    }

    float tv[TOPK]; int tn[TOPK];
    #pragma unroll
    for (int r = 0; r < TOPK; ++r) {
        float m = fmaxf(fmaxf(v0, v1), v2);
        #pragma unroll
        for (int off = 1; off < 64; off <<= 1)
            m = fmaxf(m, __shfl_xor(m, off));
        unsigned long long m0 = __ballot(v0 == m);
        unsigned long long m1 = __ballot(v1 == m);
        unsigned long long m2 = __ballot(v2 == m);
        int n;
        if (m0)      n = (int)__builtin_ctzll(m0);
        else if (m1) n = 64 + (int)__builtin_ctzll(m1);
        else         n = 128 + (int)__builtin_ctzll(m2);
        tv[r] = m; tn[r] = n;
        int kk = n >> 6, ll = n & 63;
        if (ll == lane) {
            if (kk == 0)      v0 = -2e9f;
            else if (kk == 1) v1 = -2e9f;
            else              v2 = -2e9f;
        }
    }

    float wts[TOPK]; int qn[TOPK];
    float wsum = 0.f;
    #pragma unroll
    for (int r = 0; r < TOPK; ++r) {
        float e = expf(tv[r] - tv[0]);
        wts[r] = e; wsum += e;
        int n  = tn[r];
        int dy = n / WIN - HALF;
        int dx = n - (dy + HALF) * WIN - HALF;
        int gy = min(max(py + dy, 0), HH - 1);
        int gx = min(max(px + dx, 0), WW - 1);
        qn[r]  = b * HWPIX + gy * WW + gx;
    }
    float winv = 1.0f / wsum;

    if (lane < 24) {
        const float4* base = x4 + lane * NPIX;
        float4 g = make_float4(0.f, 0.f, 0.f, 0.f);
        #pragma unroll
        for (int r = 0; r < TOPK; ++r) {
            float4 f = base[qn[r]];
            float w = wts[r];
            g.x += w * f.x; g.y += w * f.y;
            g.z += w * f.z; g.w += w * f.w;
        }
        float4 lw = ((const float4*)lnw)[lane];
        float4 lb = ((const float4*)lnb)[lane];
        float4 e;
        e.x = g.x * winv + (ownv.x - mu) * rs * lw.x + lb.x;
        e.y = g.y * winv + (ownv.y - mu) * rs * lw.y + lb.y;
        e.z = g.z * winv + (ownv.z - mu) * rs * lw.z + lb.z;
        e.w = g.w * winv + (ownv.w - mu) * rs * lw.w + lb.w;
        ((float4*)(enh + gp * CH))[lane] = e;
    }
}

// ---------------------------------------------------------------------------
// K3: fused FFN, 8 px/block, 1152 blocks x 192 thr (r19 geometry),
//     with QUAD-PACKED weights: one float4 load per inner step
//     (was 4 scalar loads). Same accumulation order -> bit-identical.
// ---------------------------------------------------------------------------
__global__ __launch_bounds__(192) void k3_ffn(
    const float* __restrict__ enh, const float4* __restrict__ w1Q,
    const float* __restrict__ b1, const float4* __restrict__ w2Q,
    const float* __restrict__ b2, float* __restrict__ out)
{
    __shared__ float hl[8][200];   // 6.25 KB, 800 B rows
    int g  = blockIdx.x;           // 1152 = 4 batches * 288 tiles
    int b  = g / 288;
    int p0 = (g % 288) * 8;
    int t  = threadIdx.x;
    const float4* ebase = (const float4*)(enh + (b * HWPIX + p0) * CH);

    // phase A: one hidden unit j for 8 block-uniform pixels
    {
        int j = t;                 // 0..191
        float a0=0.f,a1=0.f,a2=0.f,a3=0.f,a4=0.f,a5=0.f,a6=0.f,a7=0.f;
        #pragma unroll 4
        for (int c4 = 0; c4 < 24; ++c4) {
            float4 w = w1Q[c4 * 192 + j];           // one coalesced dwordx4
            float4 v0 = ebase[0*24 + c4];           // block-uniform -> s_load
            float4 v1 = ebase[1*24 + c4];
            float4 v2 = ebase[2*24 + c4];
            float4 v3 = ebase[3*24 + c4];
            float4 v4 = ebase[4*24 + c4];
            float4 v5 = ebase[5*24 + c4];
            float4 v6 = ebase[6*24 + c4];
            float4 v7 = ebase[7*24 + c4];
            a0 += v0.x*w.x + v0.y*w.y + v0.z*w.z + v0.w*w.w;
            a1 += v1.x*w.x + v1.y*w.y + v1.z*w.z + v1.w*w.w;
            a2 += v2.x*w.x + v2.y*w.y + v2.z*w.z + v2.w*w.w;
            a3 += v3.x*w.x + v3.y*w.y + v3.z*w.z + v3.w*w.w;
            a4 += v4.x*w.x + v4.y*w.y + v4.z*w.z + v4.w*w.w;
            a5 += v5.x*w.x + v5.y*w.y + v5.z*w.z + v5.w*w.w;
            a6 += v6.x*w.x + v6.y*w.y + v6.z*w.z + v6.w*w.w;
            a7 += v7.x*w.x + v7.y*w.y + v7.z*w.z + v7.w*w.w;
        }
        float bj = b1[j];
        hl[0][j] = fmaxf(a0 + bj, 0.f);
        hl[1][j] = fmaxf(a1 + bj, 0.f);
        hl[2][j] = fmaxf(a2 + bj, 0.f);
        hl[3][j] = fmaxf(a3 + bj, 0.f);
        hl[4][j] = fmaxf(a4 + bj, 0.f);
        hl[5][j] = fmaxf(a5 + bj, 0.f);
        hl[6][j] = fmaxf(a6 + bj, 0.f);
        hl[7][j] = fmaxf(a7 + bj, 0.f);
    }
    __syncthreads();

    // phase B: c = t%96, half = t/96; 4 pixels (half*4 .. half*4+3)
    {
        int c    = (t >= 96) ? t - 96 : t;
        int half = (t >= 96) ? 1 : 0;
        int q0p  = half * 4;
        const float4* h0 = (const float4*)(&hl[q0p    ][0]);
        const float4* h1 = (const float4*)(&hl[q0p + 1][0]);
        const float4* h2 = (const float4*)(&hl[q0p + 2][0]);
        const float4* h3 = (const float4*)(&hl[q0p + 3][0]);
        float s0 = 0.f, s1 = 0.f, s2 = 0.f, s3 = 0.f;
        #pragma unroll 6
        for (int j4 = 0; j4 < 48; ++j4) {
            float4 w = w2Q[j4 * 96 + c];            // one coalesced dwordx4
            float4 u0 = h0[j4], u1 = h1[j4], u2 = h2[j4], u3 = h3[j4];
            s0 += u0.x*w.x + u0.y*w.y + u0.z*w.z + u0.w*w.w;
            s1 += u1.x*w.x + u1.y*w.y + u1.z*w.z + u1.w*w.w;
            s2 += u2.x*w.x + u2.y*w.y + u2.z*w.z + u2.w*w.w;
            s3 += u3.x*w.x + u3.y*w.y + u3.z*w.z + u3.w*w.w;
        }
        float bc = b2[c];
        int pb = p0 + q0p;
        out[(b * CH + c) * HWPIX + pb + 0] =
            enh[(b * HWPIX + pb + 0) * CH + c] + s0 + bc;
        out[(b * CH + c) * HWPIX + pb + 1] =
            enh[(b * HWPIX + pb + 1) * CH + c] + s1 + bc;
        out[(b * CH + c) * HWPIX + pb + 2] =
            enh[(b * HWPIX + pb + 2) * CH + c] + s2 + bc;
        out[(b * CH + c) * HWPIX + pb + 3] =
            enh[(b * HWPIX + pb + 3) * CH + c] + s3 + bc;
    }
}

// ---------------------------------------------------------------------------
extern "C" void kernel_launch(void* const* d_in, const int* in_sizes, int n_in,
                              void* d_out, int out_size, void* d_ws, size_t ws_size,
                              hipStream_t stream)
{
    const float* x   = (const float*)d_in[0];
    const float* w1  = (const float*)d_in[1];
    const float* b1  = (const float*)d_in[2];
    const float* w2  = (const float*)d_in[3];
    const float* b2  = (const float*)d_in[4];
    const float* lnw = (const float*)d_in[5];
    const float* lnb = (const float*)d_in[6];
    float* out = (float*)d_out;

    // xt2 (chunk-major features) lives in d_out: k1 writes, k2 consumes,
    // k3 then overwrites d_out with the final output (stream-ordered).
    float* xt2 = out;

    // workspace: enh + invn + muv + rsd + w1Q + w2Q = 949,248 floats = 3.80 MB
    float* ws   = (float*)d_ws;
    float* enh  = ws;                        // NPIX*96
    float* invn = enh + NPIX * CH;           // NPIX
    float* muv  = invn + NPIX;               // NPIX
    float* rsd  = muv + NPIX;                // NPIX
    float* w1Qf = rsd + NPIX;                // 18432 floats (4608 float4)
    float* w2Qf = w1Qf + 192 * 96;           // 18432 floats

    hipLaunchKernelGGL(k0_wq, dim3(36), dim3(256), 0, stream,
                       w1, w2, (float4*)w1Qf, (float4*)w2Qf);
    hipLaunchKernelGGL(k1_prep, dim3(576), dim3(256), 0, stream,
                       x, xt2, invn, muv, rsd);
    hipLaunchKernelGGL(k2_knn, dim3(NPIX / 4), dim3(256), 0, stream,
                       xt2, invn, muv, rsd, lnw, lnb, enh);
    hipLaunchKernelGGL(k3_ffn, dim3(1152), dim3(192), 0, stream,
                       enh, (const float4*)w1Qf, b1, (const float4*)w2Qf, b2, out);
}

// Round 28
// 70.303 us; speedup vs baseline: 1.4898x; 1.0584x over previous
//
#include <hip/hip_runtime.h>
#include <math.h>

#define BATCH 4
#define CH    96
#define HH    48
#define WW    48
#define HWPIX (HH*WW)         // 2304
#define NPIX  (BATCH*HWPIX)   // 9216
#define WIN   13
#define WIN2  169
#define HALF  6
#define TOPK  8
#define NEGV  (-1000000000.0f)

// ---------------------------------------------------------------------------
// K1: merged prep. Blocks 0..575: x -> xt2 chunk-major + invn/mu/rstd
//     (r19 logic exact). Blocks 576..611: quad-pack weights (r25 k0 exact).
//     One launch instead of two; pack runs concurrently with transpose.
// ---------------------------------------------------------------------------
__global__ __launch_bounds__(256) void k1_prep(
    const float* __restrict__ x, float* __restrict__ xt2,
    float* __restrict__ invn, float* __restrict__ muv, float* __restrict__ rsd,
    const float* __restrict__ w1, const float* __restrict__ w2,
    float4* __restrict__ w1Q, float4* __restrict__ w2Q)
{
    int bid = blockIdx.x;
    int t   = threadIdx.x;

    if (bid >= 576) {
        // ---- weight packing (36 blocks * 256 thr = 9216 elements) ----
        int i = (bid - 576) * 256 + t;
        if (i < 4608) {
            int c4 = i / 192, j = i % 192;
            w1Q[c4 * 192 + j] = *(const float4*)(w1 + j * 96 + c4 * 4);
        } else {
            int k = i - 4608;
            int j4 = k / 96, c = k % 96;
            w2Q[j4 * 96 + c] = *(const float4*)(w2 + c * 192 + j4 * 4);
        }
        return;
    }

    // ---- feature prep (576 blocks, 16 px/block) ----
    __shared__ float lds[96][17];
    int b  = bid / 144;
    int p0 = (bid % 144) * 16;

    #pragma unroll
    for (int it = 0; it < 6; ++it) {
        int e = t + it * 256;      // 1536 = 96c * 16px
        int c = e >> 4;
        int p = e & 15;
        lds[c][p] = x[(b * CH + c) * HWPIX + p0 + p];
    }
    __syncthreads();

    if (t < 16) {
        float s = 0.f, ss = 0.f;
        #pragma unroll
        for (int c = 0; c < CH; ++c) { float v = lds[c][t]; s += v; ss += v * v; }
        int gpix = b * HWPIX + p0 + t;
        invn[gpix] = 1.0f / fmaxf(sqrtf(ss), 1e-12f);
        float m = s * (1.0f / 96.0f);
        muv[gpix] = m;
        rsd[gpix] = rsqrtf(ss * (1.0f / 96.0f) - m * m + 1e-5f);
    }

    float4* x4 = (float4*)xt2;
    for (int i = t; i < 384; i += 256) {
        int p = i & 15;
        int s = i >> 4;
        float4 v = make_float4(lds[4*s][p], lds[4*s+1][p],
                               lds[4*s+2][p], lds[4*s+3][p]);
        x4[s * NPIX + b * HWPIX + p0 + p] = v;
    }
}

// ---------------------------------------------------------------------------
// K2: one pixel per wave, 2304 blocks x 256 thr, chunk-major reads,
//     ballot top-8, LN stats from k1. (r16/r19 exact — best measured ~31us)
// ---------------------------------------------------------------------------
__global__ __launch_bounds__(256) void k2_knn(
    const float* __restrict__ xt2, const float* __restrict__ invn,
    const float* __restrict__ muv, const float* __restrict__ rsd,
    const float* __restrict__ lnw, const float* __restrict__ lnb,
    float* __restrict__ enh)
{
    __shared__ float own[4][96];
    int t    = threadIdx.x;
    int wv   = t >> 6;
    int lane = t & 63;
    int gp   = blockIdx.x * 4 + wv;
    int b    = gp / HWPIX;
    int p    = gp - b * HWPIX;
    int py   = p / WW;
    int px   = p - py * WW;
    const float4* x4 = (const float4*)xt2;

    float4 ownv = make_float4(0.f, 0.f, 0.f, 0.f);
    if (lane < 24) {
        ownv = x4[lane * NPIX + gp];
        ((float4*)(own[wv]))[lane] = ownv;
    }
    float inp = invn[gp];
    float mu  = muv[gp];
    float rs  = rsd[gp];

    float v0 = -2e9f, v1 = -2e9f, v2 = -2e9f;
    const float4* ov = (const float4*)(own[wv]);
    #pragma unroll
    for (int k = 0; k < 3; ++k) {
        int n = lane + 64 * k;
        float sim = -2e9f;
        if (n < WIN2) {
            int dy = n / WIN - HALF;
            int dx = n - (dy + HALF) * WIN - HALF;
            int ny = py + dy, nx = px + dx;
            if (ny >= 0 && ny < HH && nx >= 0 && nx < WW) {
                int q = b * HWPIX + ny * WW + nx;
                float inq = invn[q];
                const float4* rp = x4 + q;
                float ax = 0.f, ay = 0.f, az = 0.f, aw = 0.f;
                #pragma unroll
                for (int s = 0; s < 24; ++s) {
                    float4 a  = ov[s];
                    float4 bb = rp[s * NPIX];
                    ax += a.x * bb.x; ay += a.y * bb.y;
                    az += a.z * bb.z; aw += a.w * bb.w;
                }
                sim = ((ax + ay) + (az + aw)) * inp * inq;
            } else {
                sim = NEGV;
            }
        }
        if (k == 0) v0 = sim; else if (k == 1) v1 = sim; else v2 = sim;
    }

    float tv[TOPK]; int tn[TOPK];
    #pragma unroll
    for (int r = 0; r < TOPK; ++r) {
        float m = fmaxf(fmaxf(v0, v1), v2);
        #pragma unroll
        for (int off = 1; off < 64; off <<= 1)
            m = fmaxf(m, __shfl_xor(m, off));
        unsigned long long m0 = __ballot(v0 == m);
        unsigned long long m1 = __ballot(v1 == m);
        unsigned long long m2 = __ballot(v2 == m);
        int n;
        if (m0)      n = (int)__builtin_ctzll(m0);
        else if (m1) n = 64 + (int)__builtin_ctzll(m1);
        else         n = 128 + (int)__builtin_ctzll(m2);
        tv[r] = m; tn[r] = n;
        int kk = n >> 6, ll = n & 63;
        if (ll == lane) {
            if (kk == 0)      v0 = -2e9f;
            else if (kk == 1) v1 = -2e9f;
            else              v2 = -2e9f;
        }
    }

    float wts[TOPK]; int qn[TOPK];
    float wsum = 0.f;
    #pragma unroll
    for (int r = 0; r < TOPK; ++r) {
        float e = expf(tv[r] - tv[0]);
        wts[r] = e; wsum += e;
        int n  = tn[r];
        int dy = n / WIN - HALF;
        int dx = n - (dy + HALF) * WIN - HALF;
        int gy = min(max(py + dy, 0), HH - 1);
        int gx = min(max(px + dx, 0), WW - 1);
        qn[r]  = b * HWPIX + gy * WW + gx;
    }
    float winv = 1.0f / wsum;

    if (lane < 24) {
        const float4* base = x4 + lane * NPIX;
        float4 g = make_float4(0.f, 0.f, 0.f, 0.f);
        #pragma unroll
        for (int r = 0; r < TOPK; ++r) {
            float4 f = base[qn[r]];
            float w = wts[r];
            g.x += w * f.x; g.y += w * f.y;
            g.z += w * f.z; g.w += w * f.w;
        }
        float4 lw = ((const float4*)lnw)[lane];
        float4 lb = ((const float4*)lnb)[lane];
        float4 e;
        e.x = g.x * winv + (ownv.x - mu) * rs * lw.x + lb.x;
        e.y = g.y * winv + (ownv.y - mu) * rs * lw.y + lb.y;
        e.z = g.z * winv + (ownv.z - mu) * rs * lw.z + lb.z;
        e.w = g.w * winv + (ownv.w - mu) * rs * lw.w + lb.w;
        ((float4*)(enh + gp * CH))[lane] = e;
    }
}

// ---------------------------------------------------------------------------
// K3: fused FFN, 8 px/block, 1152 blocks x 192 thr, quad-packed weights
//     (r25 exact — best measured).
// ---------------------------------------------------------------------------
__global__ __launch_bounds__(192) void k3_ffn(
    const float* __restrict__ enh, const float4* __restrict__ w1Q,
    const float* __restrict__ b1, const float4* __restrict__ w2Q,
    const float* __restrict__ b2, float* __restrict__ out)
{
    __shared__ float hl[8][200];   // 6.25 KB, 800 B rows
    int g  = blockIdx.x;           // 1152 = 4 batches * 288 tiles
    int b  = g / 288;
    int p0 = (g % 288) * 8;
    int t  = threadIdx.x;
    const float4* ebase = (const float4*)(enh + (b * HWPIX + p0) * CH);

    // phase A: one hidden unit j for 8 block-uniform pixels
    {
        int j = t;                 // 0..191
        float a0=0.f,a1=0.f,a2=0.f,a3=0.f,a4=0.f,a5=0.f,a6=0.f,a7=0.f;
        #pragma unroll 4
        for (int c4 = 0; c4 < 24; ++c4) {
            float4 w = w1Q[c4 * 192 + j];           // one coalesced dwordx4
            float4 v0 = ebase[0*24 + c4];           // block-uniform -> s_load
            float4 v1 = ebase[1*24 + c4];
            float4 v2 = ebase[2*24 + c4];
            float4 v3 = ebase[3*24 + c4];
            float4 v4 = ebase[4*24 + c4];
            float4 v5 = ebase[5*24 + c4];
            float4 v6 = ebase[6*24 + c4];
            float4 v7 = ebase[7*24 + c4];
            a0 += v0.x*w.x + v0.y*w.y + v0.z*w.z + v0.w*w.w;
            a1 += v1.x*w.x + v1.y*w.y + v1.z*w.z + v1.w*w.w;
            a2 += v2.x*w.x + v2.y*w.y + v2.z*w.z + v2.w*w.w;
            a3 += v3.x*w.x + v3.y*w.y + v3.z*w.z + v3.w*w.w;
            a4 += v4.x*w.x + v4.y*w.y + v4.z*w.z + v4.w*w.w;
            a5 += v5.x*w.x + v5.y*w.y + v5.z*w.z + v5.w*w.w;
            a6 += v6.x*w.x + v6.y*w.y + v6.z*w.z + v6.w*w.w;
            a7 += v7.x*w.x + v7.y*w.y + v7.z*w.z + v7.w*w.w;
        }
        float bj = b1[j];
        hl[0][j] = fmaxf(a0 + bj, 0.f);
        hl[1][j] = fmaxf(a1 + bj, 0.f);
        hl[2][j] = fmaxf(a2 + bj, 0.f);
        hl[3][j] = fmaxf(a3 + bj, 0.f);
        hl[4][j] = fmaxf(a4 + bj, 0.f);
        hl[5][j] = fmaxf(a5 + bj, 0.f);
        hl[6][j] = fmaxf(a6 + bj, 0.f);
        hl[7][j] = fmaxf(a7 + bj, 0.f);
    }
    __syncthreads();

    // phase B: c = t%96, half = t/96; 4 pixels (half*4 .. half*4+3)
    {
        int c    = (t >= 96) ? t - 96 : t;
        int half = (t >= 96) ? 1 : 0;
        int q0p  = half * 4;
        const float4* h0 = (const float4*)(&hl[q0p    ][0]);
        const float4* h1 = (const float4*)(&hl[q0p + 1][0]);
        const float4* h2 = (const float4*)(&hl[q0p + 2][0]);
        const float4* h3 = (const float4*)(&hl[q0p + 3][0]);
        float s0 = 0.f, s1 = 0.f, s2 = 0.f, s3 = 0.f;
        #pragma unroll 6
        for (int j4 = 0; j4 < 48; ++j4) {
            float4 w = w2Q[j4 * 96 + c];            // one coalesced dwordx4
            float4 u0 = h0[j4], u1 = h1[j4], u2 = h2[j4], u3 = h3[j4];
            s0 += u0.x*w.x + u0.y*w.y + u0.z*w.z + u0.w*w.w;
            s1 += u1.x*w.x + u1.y*w.y + u1.z*w.z + u1.w*w.w;
            s2 += u2.x*w.x + u2.y*w.y + u2.z*w.z + u2.w*w.w;
            s3 += u3.x*w.x + u3.y*w.y + u3.z*w.z + u3.w*w.w;
        }
        float bc = b2[c];
        int pb = p0 + q0p;
        out[(b * CH + c) * HWPIX + pb + 0] =
            enh[(b * HWPIX + pb + 0) * CH + c] + s0 + bc;
        out[(b * CH + c) * HWPIX + pb + 1] =
            enh[(b * HWPIX + pb + 1) * CH + c] + s1 + bc;
        out[(b * CH + c) * HWPIX + pb + 2] =
            enh[(b * HWPIX + pb + 2) * CH + c] + s2 + bc;
        out[(b * CH + c) * HWPIX + pb + 3] =
            enh[(b * HWPIX + pb + 3) * CH + c] + s3 + bc;
    }
}

// ---------------------------------------------------------------------------
extern "C" void kernel_launch(void* const* d_in, const int* in_sizes, int n_in,
                              void* d_out, int out_size, void* d_ws, size_t ws_size,
                              hipStream_t stream)
{
    const float* x   = (const float*)d_in[0];
    const float* w1  = (const float*)d_in[1];
    const float* b1  = (const float*)d_in[2];
    const float* w2  = (const float*)d_in[3];
    const float* b2  = (const float*)d_in[4];
    const float* lnw = (const float*)d_in[5];
    const float* lnb = (const float*)d_in[6];
    float* out = (float*)d_out;

    // xt2 (chunk-major features) lives in d_out: k1 writes, k2 consumes,
    // k3 then overwrites d_out with the final output (stream-ordered).
    float* xt2 = out;

    // workspace: enh + invn + muv + rsd + w1Q + w2Q = 949,248 floats = 3.80 MB
    float* ws   = (float*)d_ws;
    float* enh  = ws;                        // NPIX*96
    float* invn = enh + NPIX * CH;           // NPIX
    float* muv  = invn + NPIX;               // NPIX
    float* rsd  = muv + NPIX;                // NPIX
    float* w1Qf = rsd + NPIX;                // 18432 floats (4608 float4)
    float* w2Qf = w1Qf + 192 * 96;           // 18432 floats

    hipLaunchKernelGGL(k1_prep, dim3(612), dim3(256), 0, stream,
                       x, xt2, invn, muv, rsd,
                       w1, w2, (float4*)w1Qf, (float4*)w2Qf);
    hipLaunchKernelGGL(k2_knn, dim3(NPIX / 4), dim3(256), 0, stream,
                       xt2, invn, muv, rsd, lnw, lnb, enh);
    hipLaunchKernelGGL(k3_ffn, dim3(1152), dim3(192), 0, stream,
                       enh, (const float4*)w1Qf, b1, (const float4*)w2Qf, b2, out);
}